// Round 10
// baseline (24791.263 us; speedup 1.0000x reference)
//
#include <hip/hip_runtime.h>
#include <hip/hip_fp16.h>
#include <stdint.h>

// LSTM_29042568856007: B=64, T=4096, D=256, H=256.
// Round 14: hide the MALL relay under an INDEPENDENT recurrence. R13 showed
// one group's step has only ~500 cyc of h-independent work vs a ~2.5-4k cyc
// cross-CU h relay; and W_hh (512 KB) = a CU's whole register file, so a
// no-communication design can't exist. Fix: each WG time-interleaves TWO
// batch-groups A,B sharing the same weight frags (weights are batch-
// independent): phase(A,t) publishes A.h(t+1), then phase(B,t) runs a full
// phase of B work before A polls again -> relay window ~1.5-2k cyc of real
// work. Grid 16 = 4 parts x 4 group-pairs. Everything else is R11/R13
// verbatim: tagged-u64 agent-scope exchange (MALL), double-buffered hg,
// R9-verified frag layout + ew/gather, per-phase split (h-MFMA critical,
// x-MFMA seeds next acc). Buffer-safety induction unchanged per group.

#define LSTM_B 64
#define LSTM_T 4096
#define LSTM_D 256
#define LSTM_H 256

#define WS_HG_OFF (1u << 20)
// hg: uint64 [8 g][2 buf][8 m][128 jp]; entry = tag<<32 | f16 h-pair. 128 KB.

typedef __attribute__((ext_vector_type(8))) _Float16 half8;
typedef __attribute__((ext_vector_type(4))) float f32x4;

#define AST64(p, v) __hip_atomic_store((p), (v), __ATOMIC_RELAXED, __HIP_MEMORY_SCOPE_AGENT)
#define ALD64(p)    __hip_atomic_load((p), __ATOMIC_RELAXED, __HIP_MEMORY_SCOPE_AGENT)
#define BARLG()     asm volatile("s_waitcnt lgkmcnt(0)\n\ts_barrier" ::: "memory")

static __device__ __forceinline__ float sigmoidf_(float x) {
    return 1.0f / (1.0f + __expf(-x));
}
static __device__ __forceinline__ float tanhf_(float x) {
    float ax = fabsf(x);
    float e  = __expf(-2.0f * ax);
    float t  = (1.0f - e) / (1.0f + e);
    return copysignf(t, x);
}

// ws frags: uint4 frag[T=64][kk=16][lane=64]; identical to R9/R11/R13.
__global__ __launch_bounds__(256) void prep_frags(
    const float* __restrict__ W_ih, const float* __restrict__ W_hh,
    uint8_t* __restrict__ ws)
{
    int idx = blockIdx.x * blockDim.x + threadIdx.x;   // [0, 65536)
    uint4* Wp = (uint4*)ws;
    int lane = idx & 63;
    int kk   = (idx >> 6) & 15;
    int T    = idx >> 10;
    int n  = T * 16 + (lane & 15);
    int r  = ((n & 3) << 8) + (n >> 2);
    int kb = 32 * kk + 4 * (lane >> 4);
    uint32_t u[4];
    #pragma unroll
    for (int h = 0; h < 4; ++h) {
        uint32_t lohi[2];
        #pragma unroll
        for (int e = 0; e < 2; ++e) {
            int j = 2 * h + e;
            int k = kb + (j & 3) + 16 * (j >> 2);
            float v = (k < 256) ? W_hh[r * 256 + k] : W_ih[r * 256 + (k - 256)];
            lohi[e] = (uint32_t)__half_as_ushort(__float2half(v));
        }
        u[h] = lohi[0] | (lohi[1] << 16);
    }
    Wp[idx] = make_uint4(u[0], u[1], u[2], u[3]);
    // re-zero hg each launch: tag 0 == "h(0)=0 ready" for the t=0 poll.
    if (idx < 32768) ((uint32_t*)(ws + WS_HG_OFF))[idx] = 0u;
}

__global__ __launch_bounds__(256, 1) void lstm_r14(
    const float* __restrict__ xs,      // [B, T, D] fp32
    const float* __restrict__ bias_g,  // [4H]
    uint8_t* __restrict__ ws,
    float* __restrict__ out)           // h[B,H] then c[B,H]
{
    const int tid = threadIdx.x;
    const int l   = tid & 63;
    const int w   = tid >> 6;            // wave [0,4)
    const int G   = blockIdx.x & 3;      // group-pair
    const int p   = blockIdx.x >> 2;     // slot-part: slots 256p..256p+255
    const int gA  = 2 * G;               // batches 8gA..8gA+7
    const int gB  = 2 * G + 1;           // batches 8gB..8gB+7

    const uint4* WF = (const uint4*)ws;
    uint64_t* hg64  = (uint64_t*)(ws + WS_HG_OFF);

    __shared__ uint4 hx2[2 * 16 * 64];   // per-group A-frag areas, 32 KiB
    uint8_t* hxA = (uint8_t*)hx2;
    uint8_t* hxB = (uint8_t*)hx2 + 16384;

    // ---- one-time: this WG's 64 B-frags into registers (R9-verified) ----
    uint4 wf[4][16];
    #pragma unroll
    for (int tl = 0; tl < 4; ++tl) {
        int T = p * 16 + w * 4 + tl;
        #pragma unroll
        for (int kk = 0; kk < 16; ++kk)
            wf[tl][kk] = WF[(T * 16 + kk) * 64 + l];
    }
    #pragma unroll
    for (int tl = 0; tl < 4; ++tl)
        #pragma unroll
        for (int kk = 0; kk < 16; ++kk)
            asm volatile("" : "+v"(wf[tl][kk].x), "+v"(wf[tl][kk].y),
                              "+v"(wf[tl][kk].z), "+v"(wf[tl][kk].w));

    // ---- per-lane ew constants (R9-verified) ----
    const int  c2   = l & 3;
    const int  qa   = l >> 4;
    const bool c2b0 = (c2 & 1) != 0, c2b1 = (c2 & 2) != 0;
    const int  m_ew = 4 * qa + c2;       // batch row this lane finalizes
    float bias[4];
    int   jj[4];
    #pragma unroll
    for (int tl = 0; tl < 4; ++tl) {
        int T    = p * 16 + w * 4 + tl;
        int slot = T * 16 + (l & 15);
        int r    = ((slot & 3) << 8) + (slot >> 2);
        bias[tl] = bias_g[r];
        jj[tl]   = slot >> 2;            // global h-col [0,256)
    }

    // ---- staging ids ----
    const int m_s = tid >> 4;            // [0,16); only <8 are real batches
    const int d0  = (tid & 15) * 16;
    const float* xrowA = xs + (size_t)(8 * gA + (m_s & 7)) * LSTM_T * LSTM_D + d0;
    const float* xrowB = xs + (size_t)(8 * gB + (m_s & 7)) * LSTM_T * LSTM_D + d0;

    // ---- prologue: zero hx2; stage x(0) both; prefetch x(1) both ----
    #pragma unroll
    for (int i = 0; i < 8; ++i)
        hx2[tid + i * 256] = make_uint4(0, 0, 0, 0);
    float4 xbA[4], xbB[4];
    if (m_s < 8) {
        #pragma unroll
        for (int i = 0; i < 4; ++i) {
            float4 xvA = ((const float4*)xrowA)[i];
            float4 xvB = ((const float4*)xrowB)[i];
            int k0 = 256 + d0 + 4 * i;
            int kk = k0 >> 5, off = k0 & 31;
            int q = (off & 15) >> 2, hi = off >> 4;
            int slot = (m_s + 16 * q) ^ ((2 * kk) & 63);
            __half2 a0 = __floats2half2_rn(xvA.x, xvA.y);
            __half2 a1 = __floats2half2_rn(xvA.z, xvA.w);
            uint64_t va = (uint64_t)__builtin_bit_cast(uint32_t, a0)
                        | ((uint64_t)__builtin_bit_cast(uint32_t, a1) << 32);
            *(uint64_t*)(hxA + kk * 1024 + slot * 16 + hi * 8) = va;
            __half2 b0 = __floats2half2_rn(xvB.x, xvB.y);
            __half2 b1 = __floats2half2_rn(xvB.z, xvB.w);
            uint64_t vb = (uint64_t)__builtin_bit_cast(uint32_t, b0)
                        | ((uint64_t)__builtin_bit_cast(uint32_t, b1) << 32);
            *(uint64_t*)(hxB + kk * 1024 + slot * 16 + hi * 8) = vb;
        }
        #pragma unroll
        for (int i = 0; i < 4; ++i) {
            xbA[i] = ((const float4*)(xrowA + (size_t)1 * LSTM_D))[i];
            xbB[i] = ((const float4*)(xrowB + (size_t)1 * LSTM_D))[i];
        }
    }
    BARLG();

    // ---- seed acc = bias + x(0)-half for both groups ----
    f32x4 accA[4], accB[4];
    #pragma unroll
    for (int tl = 0; tl < 4; ++tl) {
        accA[tl] = (f32x4){bias[tl], bias[tl], bias[tl], bias[tl]};
        accB[tl] = accA[tl];
    }
    #pragma unroll
    for (int kx = 0; kx < 8; ++kx) {
        int kk = kx + 8;
        uint4 fa = *(const uint4*)(hxA + (kk * 64 + (l ^ ((2 * kk) & 63))) * 16);
        uint4 fb = *(const uint4*)(hxB + (kk * 64 + (l ^ ((2 * kk) & 63))) * 16);
        #pragma unroll
        for (int tl = 0; tl < 4; ++tl) {
            accA[tl] = __builtin_amdgcn_mfma_f32_16x16x32_f16(
                __builtin_bit_cast(half8, fa), __builtin_bit_cast(half8, wf[tl][kk]), accA[tl], 0, 0, 0);
            accB[tl] = __builtin_amdgcn_mfma_f32_16x16x32_f16(
                __builtin_bit_cast(half8, fb), __builtin_bit_cast(half8, wf[tl][kk]), accB[tl], 0, 0, 0);
        }
    }

    float cstA[4] = {0, 0, 0, 0}, hstA[4] = {0, 0, 0, 0};
    float cstB[4] = {0, 0, 0, 0}, hstB[4] = {0, 0, 0, 0};

#define PHASE(GID, HXB, ACC, CST, HST, XB, XROW, T_) do {                           \
    /* 1: poll h(T_) (tag>=T_; t=0 passes on zeroed hg) + stage to LDS */           \
    if (m_s < 8) {                                                                  \
        const int bufp = (T_) & 1;                                                  \
        const uint32_t tgt = (uint32_t)(T_);                                        \
        uint64_t* hgr = hg64 + (((size_t)(GID) * 2 + bufp) * 8 + m_s) * 128         \
                      + (d0 >> 1);                                                  \
        uint64_t hv[8];                                                             \
        _Pragma("unroll")                                                           \
        for (int i = 0; i < 8; ++i) hv[i] = ALD64(&hgr[i]);                         \
        int spin = 0;                                                               \
        while (true) {                                                              \
            bool ok = true;                                                         \
            _Pragma("unroll")                                                       \
            for (int i = 0; i < 8; ++i) ok &= ((uint32_t)(hv[i] >> 32) >= tgt);     \
            if (ok || ++spin > 4000) break;                                         \
            _Pragma("unroll")                                                       \
            for (int i = 0; i < 8; ++i) hv[i] = ALD64(&hgr[i]);                     \
        }                                                                           \
        _Pragma("unroll")                                                           \
        for (int i = 0; i < 8; ++i) {                                               \
            uint32_t pr = (uint32_t)hv[i];                                          \
            int k0 = d0 + 2 * i;                                                    \
            int kk = k0 >> 5, off = k0 & 31;                                        \
            int q = (off & 15) >> 2, hi = off >> 4;                                 \
            int slot = (m_s + 16 * q) ^ ((2 * kk) & 63);                            \
            *(uint32_t*)((HXB) + kk * 1024 + slot * 16 + hi * 8                     \
                         + ((off & 3) << 1)) = pr;                                  \
        }                                                                           \
    }                                                                               \
    BARLG();                                                                        \
    /* 2: h-MFMAs (acc pre-seeded with bias + x(T_)) */                             \
    {                                                                               \
        uint4 afh[8];                                                               \
        _Pragma("unroll")                                                           \
        for (int kk = 0; kk < 8; ++kk)                                              \
            afh[kk] = *(const uint4*)((HXB) + (kk * 64 + (l ^ ((2 * kk) & 63))) * 16);\
        _Pragma("unroll")                                                           \
        for (int kk = 0; kk < 8; ++kk) {                                            \
            half8 a = __builtin_bit_cast(half8, afh[kk]);                           \
            _Pragma("unroll")                                                       \
            for (int tl = 0; tl < 4; ++tl)                                          \
                ACC[tl] = __builtin_amdgcn_mfma_f32_16x16x32_f16(                   \
                    a, __builtin_bit_cast(half8, wf[tl][kk]), ACC[tl], 0, 0, 0);    \
        }                                                                           \
    }                                                                               \
    /* 3: gather + ew + pack (R9-verified) */                                       \
    uint32_t hpair[4];                                                              \
    _Pragma("unroll")                                                               \
    for (int tl = 0; tl < 4; ++tl) {                                                \
        f32x4 a = ACC[tl];                                                          \
        float s01  = c2b0 ? a.y : a.x;                                              \
        float s23  = c2b0 ? a.w : a.z;                                              \
        float s01b = c2b0 ? a.x : a.y;                                              \
        float s23b = c2b0 ? a.z : a.w;                                              \
        float own = c2b1 ? s23  : s01;                                              \
        float v1  = c2b1 ? s23b : s01b;                                             \
        float v2  = c2b1 ? s01  : s23;                                              \
        float v3  = c2b1 ? s01b : s23b;                                             \
        float r1 = __shfl_xor(v1, 1, 64);                                           \
        float r2 = __shfl_xor(v2, 2, 64);                                           \
        float r3 = __shfl_xor(v3, 3, 64);                                           \
        float gi = c2b1 ? (c2b0 ? r3 : r2) : (c2b0 ? r1 : own);                     \
        float gf = c2b1 ? (c2b0 ? r2 : r3) : (c2b0 ? own : r1);                     \
        float gg = c2b1 ? (c2b0 ? r1 : own) : (c2b0 ? r3 : r2);                     \
        float go = c2b1 ? (c2b0 ? own : r1) : (c2b0 ? r2 : r3);                     \
        float cc = CST[tl];                                                         \
        cc = sigmoidf_(gf) * cc + sigmoidf_(gi) * tanhf_(gg);                       \
        float hh = sigmoidf_(go) * tanhf_(cc);                                      \
        CST[tl] = cc; HST[tl] = hh;                                                 \
        uint32_t u  = (uint32_t)__half_as_ushort(__float2half(hh));                 \
        uint32_t up = (uint32_t)__shfl_xor((int)u, 4, 64);                          \
        hpair[tl] = (u & 0xffffu) | (up << 16);                                     \
    }                                                                               \
    /* 4: publish h(T_+1) (tagged u64, agent scope -> MALL) */                      \
    {                                                                               \
        const int bufn = ((T_) + 1) & 1;                                            \
        if (l < 32 && (l & 4) == 0) {                                               \
            uint64_t* hgrow = hg64 + (((size_t)(GID) * 2 + bufn) * 8 + m_ew) * 128; \
            const uint64_t tagw = ((uint64_t)(uint32_t)((T_) + 1)) << 32;           \
            _Pragma("unroll")                                                       \
            for (int tl = 0; tl < 4; ++tl)                                          \
                AST64(&hgrow[jj[tl] >> 1], tagw | (uint64_t)hpair[tl]);             \
        }                                                                           \
    }                                                                               \
    /* 5: stage x(T_+1); reload XB <- x(T_+2) */                                    \
    if (m_s < 8) {                                                                  \
        _Pragma("unroll")                                                           \
        for (int i = 0; i < 4; ++i) {                                               \
            float4 xv = XB[i];                                                      \
            __half2 h0 = __floats2half2_rn(xv.x, xv.y);                             \
            __half2 h1 = __floats2half2_rn(xv.z, xv.w);                             \
            uint64_t v = (uint64_t)__builtin_bit_cast(uint32_t, h0)                 \
                       | ((uint64_t)__builtin_bit_cast(uint32_t, h1) << 32);        \
            int k0 = 256 + d0 + 4 * i;                                              \
            int kk = k0 >> 5, off = k0 & 31;                                        \
            int q = (off & 15) >> 2, hi = off >> 4;                                 \
            int slot = (m_s + 16 * q) ^ ((2 * kk) & 63);                            \
            *(uint64_t*)((HXB) + kk * 1024 + slot * 16 + hi * 8) = v;               \
        }                                                                           \
        int tn = ((T_) + 2 < LSTM_T) ? (T_) + 2 : LSTM_T - 1;                       \
        const float4* nx = (const float4*)((XROW) + (size_t)tn * LSTM_D);           \
        _Pragma("unroll")                                                           \
        for (int i = 0; i < 4; ++i) XB[i] = nx[i];                                  \
    }                                                                               \
    BARLG();                                                                        \
    /* 6: seed ACC = bias + x(T_+1)-half for next phase of this group */            \
    {                                                                               \
        uint4 afx[8];                                                               \
        _Pragma("unroll")                                                           \
        for (int kx = 0; kx < 8; ++kx) {                                            \
            int kk = kx + 8;                                                        \
            afx[kx] = *(const uint4*)((HXB) + (kk * 64 + (l ^ ((2 * kk) & 63))) * 16);\
        }                                                                           \
        _Pragma("unroll")                                                           \
        for (int tl = 0; tl < 4; ++tl)                                              \
            ACC[tl] = (f32x4){bias[tl], bias[tl], bias[tl], bias[tl]};              \
        _Pragma("unroll")                                                           \
        for (int kx = 0; kx < 8; ++kx) {                                            \
            half8 a = __builtin_bit_cast(half8, afx[kx]);                           \
            _Pragma("unroll")                                                       \
            for (int tl = 0; tl < 4; ++tl)                                          \
                ACC[tl] = __builtin_amdgcn_mfma_f32_16x16x32_f16(                   \
                    a, __builtin_bit_cast(half8, wf[tl][kx + 8]), ACC[tl], 0, 0, 0);\
        }                                                                           \
    }                                                                               \
} while (0)

    for (int t = 0; t < LSTM_T; ++t) {
        PHASE(gA, hxA, accA, cstA, hstA, xbA, xrowA, t);
        PHASE(gB, hxB, accB, cstB, hstB, xbB, xrowB, t);
    }
#undef PHASE

    if (m_ew < 8) {
        #pragma unroll
        for (int tl = 0; tl < 4; ++tl) {
            int ba = 8 * gA + m_ew;
            int bb = 8 * gB + m_ew;
            out[ba * LSTM_H + jj[tl]]                   = hstA[tl];
            out[LSTM_B * LSTM_H + ba * LSTM_H + jj[tl]] = cstA[tl];
            out[bb * LSTM_H + jj[tl]]                   = hstB[tl];
            out[LSTM_B * LSTM_H + bb * LSTM_H + jj[tl]] = cstB[tl];
        }
    }
}

extern "C" void kernel_launch(void* const* d_in, const int* in_sizes, int n_in,
                              void* d_out, int out_size, void* d_ws, size_t ws_size,
                              hipStream_t stream) {
    const float* xs   = (const float*)d_in[0];  // [64,4096,256]
    const float* W_ih = (const float*)d_in[1];  // [1024,256]
    const float* W_hh = (const float*)d_in[2];  // [1024,256]
    const float* b    = (const float*)d_in[3];  // [1024]
    float* out = (float*)d_out;
    uint8_t* ws = (uint8_t*)d_ws;

    prep_frags<<<256, 256, 0, stream>>>(W_ih, W_hh, ws);
    lstm_r14<<<16, 256, 0, stream>>>(xs, b, ws, out);
}

// Round 11
// 11800.167 us; speedup vs baseline: 2.1009x; 2.1009x over previous
//
#include <hip/hip_runtime.h>
#include <hip/hip_fp16.h>
#include <stdint.h>

// LSTM_29042568856007: B=64, T=4096, D=256, H=256.
// Round 15: R13 verbatim EXCEPT the poll. R14's decisive result: a full
// independent phase (~7k cyc) inserted between publish and poll changed
// per-phase time NOT AT ALL (3.02us vs R13's 3.01us step) -> the wait is not
// publish->visibility latency; it's the poll itself. 8 __hip_atomic_loads
// are ordered ops: compiler issues each as its own global_load + waitcnt ->
// 8 SERIAL MALL round-trips ~6.4k cyc = the constant cost seen in R11/R13/
// R14. Fix: each thread's 8 u64s are one 64B-aligned cacheline -> issue
// 4x global_load_dwordx4 sc1 (agent-scope bit, same semantics the compiler
// uses for agent atomics; R12's failure used the WRONG bit sc0) + ONE
// s_waitcnt vmcnt(0) per retry ~= 1 MALL RT. No tearing within an aligned
// u64 inside a single cacheline read. Publish side unchanged (proven AST64).
// Everything else (frag layout, phase split, ew/gather, buffer safety,
// prep) identical to R13.

#define LSTM_B 64
#define LSTM_T 4096
#define LSTM_D 256
#define LSTM_H 256

#define WS_HG_OFF (1u << 20)
// hg: uint64 [8 g][2 buf][8 m][128 jp]; entry = tag<<32 | f16 h-pair. 128 KB.

typedef __attribute__((ext_vector_type(8))) _Float16 half8;
typedef __attribute__((ext_vector_type(4))) float f32x4;
typedef __attribute__((ext_vector_type(4))) uint32_t u32x4;

#define AST64(p, v) __hip_atomic_store((p), (v), __ATOMIC_RELAXED, __HIP_MEMORY_SCOPE_AGENT)
#define BARLG()     asm volatile("s_waitcnt lgkmcnt(0)\n\ts_barrier" ::: "memory")

static __device__ __forceinline__ float sigmoidf_(float x) {
    return 1.0f / (1.0f + __expf(-x));
}
static __device__ __forceinline__ float tanhf_(float x) {
    float ax = fabsf(x);
    float e  = __expf(-2.0f * ax);
    float t  = (1.0f - e) / (1.0f + e);
    return copysignf(t, x);
}

// One-cacheline agent-coherent read: 4 parallel dwordx4 loads with sc1
// (device/agent scope -- the bit the compiler emits for agent atomics),
// single waitcnt. ~1 MALL RT instead of 8 serial ones.
static __device__ __forceinline__ void ld64B_agent(const uint64_t* p, uint64_t* v) {
    u32x4 a, b, c, d;
    asm volatile(
        "global_load_dwordx4 %0, %4, off sc1\n\t"
        "global_load_dwordx4 %1, %4, off offset:16 sc1\n\t"
        "global_load_dwordx4 %2, %4, off offset:32 sc1\n\t"
        "global_load_dwordx4 %3, %4, off offset:48 sc1\n\t"
        "s_waitcnt vmcnt(0)"
        : "=&v"(a), "=&v"(b), "=&v"(c), "=&v"(d)
        : "v"(p) : "memory");
    v[0] = ((uint64_t)a.y << 32) | a.x;
    v[1] = ((uint64_t)a.w << 32) | a.z;
    v[2] = ((uint64_t)b.y << 32) | b.x;
    v[3] = ((uint64_t)b.w << 32) | b.z;
    v[4] = ((uint64_t)c.y << 32) | c.x;
    v[5] = ((uint64_t)c.w << 32) | c.z;
    v[6] = ((uint64_t)d.y << 32) | d.x;
    v[7] = ((uint64_t)d.w << 32) | d.z;
}

// ws frags: uint4 frag[T=64][kk=16][lane=64]; identical to R9/R11/R13.
// slot n = T*16 + (lane&15); source gate row r = (n&3)*256 + (n>>2);
// k = 32*kk + 4*(lane>>4) + (j&3) + 16*(j>>2); k<256 -> W_hh else W_ih.
__global__ __launch_bounds__(256) void prep_frags(
    const float* __restrict__ W_ih, const float* __restrict__ W_hh,
    uint8_t* __restrict__ ws)
{
    int idx = blockIdx.x * blockDim.x + threadIdx.x;   // [0, 65536)
    uint4* Wp = (uint4*)ws;
    int lane = idx & 63;
    int kk   = (idx >> 6) & 15;
    int T    = idx >> 10;
    int n  = T * 16 + (lane & 15);
    int r  = ((n & 3) << 8) + (n >> 2);
    int kb = 32 * kk + 4 * (lane >> 4);
    uint32_t u[4];
    #pragma unroll
    for (int h = 0; h < 4; ++h) {
        uint32_t lohi[2];
        #pragma unroll
        for (int e = 0; e < 2; ++e) {
            int j = 2 * h + e;
            int k = kb + (j & 3) + 16 * (j >> 2);
            float v = (k < 256) ? W_hh[r * 256 + k] : W_ih[r * 256 + (k - 256)];
            lohi[e] = (uint32_t)__half_as_ushort(__float2half(v));
        }
        u[h] = lohi[0] | (lohi[1] << 16);
    }
    Wp[idx] = make_uint4(u[0], u[1], u[2], u[3]);
    // re-zero hg each launch (graph replay: stale tags must not survive)
    if (idx < 32768) ((uint32_t*)(ws + WS_HG_OFF))[idx] = 0u;
}

__global__ __launch_bounds__(256, 1) void lstm_r15(
    const float* __restrict__ xs,      // [B, T, D] fp32
    const float* __restrict__ bias_g,  // [4H]
    uint8_t* __restrict__ ws,
    float* __restrict__ out)           // h[B,H] then c[B,H]
{
    const int tid = threadIdx.x;
    const int l   = tid & 63;
    const int w   = tid >> 6;            // wave [0,4)
    const int g   = blockIdx.x & 7;      // group: batches 8g..8g+7
    const int p   = blockIdx.x >> 3;     // slot-part: slots 256p..256p+255

    const uint4* WF = (const uint4*)ws;
    uint64_t* hg64  = (uint64_t*)(ws + WS_HG_OFF);

    __shared__ uint4 hx[16 * 64];        // A-frags [kk][laneSlot]; kk<8 = h, kk>=8 = x

    // ---- one-time: this WG's 64 B-frags into registers (R9-verified) ----
    uint4 wf[4][16];
    #pragma unroll
    for (int tl = 0; tl < 4; ++tl) {
        int T = p * 16 + w * 4 + tl;
        #pragma unroll
        for (int kk = 0; kk < 16; ++kk)
            wf[tl][kk] = WF[(T * 16 + kk) * 64 + l];
    }
    #pragma unroll
    for (int tl = 0; tl < 4; ++tl)
        #pragma unroll
        for (int kk = 0; kk < 16; ++kk)
            asm volatile("" : "+v"(wf[tl][kk].x), "+v"(wf[tl][kk].y),
                              "+v"(wf[tl][kk].z), "+v"(wf[tl][kk].w));

    // ---- per-lane ew constants (R9-verified; D: col=l&15, row=4*(l>>4)+reg) ----
    const int  c2   = l & 3;
    const int  qa   = l >> 4;
    const bool c2b0 = (c2 & 1) != 0, c2b1 = (c2 & 2) != 0;
    const int  m_ew = 4 * qa + c2;       // batch row this lane finalizes
    float bias[4];
    int   jj[4];
    #pragma unroll
    for (int tl = 0; tl < 4; ++tl) {
        int T    = p * 16 + w * 4 + tl;
        int slot = T * 16 + (l & 15);
        int r    = ((slot & 3) << 8) + (slot >> 2);
        bias[tl] = bias_g[r];
        jj[tl]   = slot >> 2;            // global h-col [0,256)
    }

    // ---- staging ids: thread covers (m_s, cols d0..d0+15) ----
    const int m_s = tid >> 4;            // [0,16); only <8 are real batches
    const int d0  = (tid & 15) * 16;
    const float* xrow = xs + (size_t)(8 * g + (m_s & 7)) * LSTM_T * LSTM_D + d0;

    // ---- prologue: zero hx; stage x(0); prefetch x(1),x(2) ----
    hx[tid]       = make_uint4(0, 0, 0, 0);
    hx[tid + 256] = make_uint4(0, 0, 0, 0);
    hx[tid + 512] = make_uint4(0, 0, 0, 0);
    hx[tid + 768] = make_uint4(0, 0, 0, 0);
    float4 xb[2][4];
    if (m_s < 8) {
        #pragma unroll
        for (int i = 0; i < 4; ++i) {
            float4 xv = ((const float4*)xrow)[i];
            __half2 h0 = __floats2half2_rn(xv.x, xv.y);
            __half2 h1 = __floats2half2_rn(xv.z, xv.w);
            uint64_t v = (uint64_t)__builtin_bit_cast(uint32_t, h0)
                       | ((uint64_t)__builtin_bit_cast(uint32_t, h1) << 32);
            int k0 = 256 + d0 + 4 * i;
            int kk = k0 >> 5, off = k0 & 31;
            int q = (off & 15) >> 2, hi = off >> 4;
            int slot = (m_s + 16 * q) ^ ((2 * kk) & 63);
            *(uint64_t*)((uint8_t*)hx + kk * 1024 + slot * 16 + hi * 8) = v;
        }
        #pragma unroll
        for (int i = 0; i < 4; ++i) xb[0][i] = ((const float4*)(xrow + (size_t)1 * LSTM_D))[i];
        #pragma unroll
        for (int i = 0; i < 4; ++i) xb[1][i] = ((const float4*)(xrow + (size_t)2 * LSTM_D))[i];
    }
    BARLG();                             // x(0) staged

    // ---- seed accA = bias + x(0)-half (kk 8..15) ----
    f32x4 accA[4], accB[4];
    {
        uint4 afx[8];
        #pragma unroll
        for (int kx = 0; kx < 8; ++kx) {
            int kk = kx + 8;
            afx[kx] = hx[kk * 64 + (l ^ ((2 * kk) & 63))];
        }
        #pragma unroll
        for (int tl = 0; tl < 4; ++tl)
            accA[tl] = (f32x4){bias[tl], bias[tl], bias[tl], bias[tl]};
        #pragma unroll
        for (int kx = 0; kx < 8; ++kx) {
            half8 a = __builtin_bit_cast(half8, afx[kx]);
            #pragma unroll
            for (int tl = 0; tl < 4; ++tl)
                accA[tl] = __builtin_amdgcn_mfma_f32_16x16x32_f16(
                    a, __builtin_bit_cast(half8, wf[tl][kx + 8]), accA[tl], 0, 0, 0);
        }
    }

    float cst[4] = {0, 0, 0, 0}, hst[4] = {0, 0, 0, 0};

#define STEP(T_, PAR, ACC_C, ACC_N) do {                                            \
    /* ---- phase A (critical): h-half MFMA -> ew -> publish ---- */                \
    uint4 afh[8];                                                                   \
    _Pragma("unroll")                                                               \
    for (int kk = 0; kk < 8; ++kk)                                                  \
        afh[kk] = hx[kk * 64 + (l ^ ((2 * kk) & 63))];                              \
    _Pragma("unroll")                                                               \
    for (int kk = 0; kk < 8; ++kk) {                                                \
        half8 a = __builtin_bit_cast(half8, afh[kk]);                               \
        _Pragma("unroll")                                                           \
        for (int tl = 0; tl < 4; ++tl)                                              \
            ACC_C[tl] = __builtin_amdgcn_mfma_f32_16x16x32_f16(                     \
                a, __builtin_bit_cast(half8, wf[tl][kk]), ACC_C[tl], 0, 0, 0);      \
    }                                                                               \
    uint32_t hpair[4];                                                              \
    _Pragma("unroll")                                                               \
    for (int tl = 0; tl < 4; ++tl) {                                                \
        f32x4 a = ACC_C[tl];                                                        \
        float s01  = c2b0 ? a.y : a.x;                                              \
        float s23  = c2b0 ? a.w : a.z;                                              \
        float s01b = c2b0 ? a.x : a.y;                                              \
        float s23b = c2b0 ? a.z : a.w;                                              \
        float own = c2b1 ? s23  : s01;                                              \
        float v1  = c2b1 ? s23b : s01b;                                             \
        float v2  = c2b1 ? s01  : s23;                                              \
        float v3  = c2b1 ? s01b : s23b;                                             \
        float r1 = __shfl_xor(v1, 1, 64);                                           \
        float r2 = __shfl_xor(v2, 2, 64);                                           \
        float r3 = __shfl_xor(v3, 3, 64);                                           \
        float gi = c2b1 ? (c2b0 ? r3 : r2) : (c2b0 ? r1 : own);                     \
        float gf = c2b1 ? (c2b0 ? r2 : r3) : (c2b0 ? own : r1);                     \
        float gg = c2b1 ? (c2b0 ? r1 : own) : (c2b0 ? r3 : r2);                     \
        float go = c2b1 ? (c2b0 ? own : r1) : (c2b0 ? r2 : r3);                     \
        float cc = cst[tl];                                                         \
        cc = sigmoidf_(gf) * cc + sigmoidf_(gi) * tanhf_(gg);                       \
        float hh = sigmoidf_(go) * tanhf_(cc);                                      \
        cst[tl] = cc; hst[tl] = hh;                                                 \
        uint32_t u  = (uint32_t)__half_as_ushort(__float2half(hh));                 \
        uint32_t up = (uint32_t)__shfl_xor((int)u, 4, 64);                          \
        hpair[tl] = (u & 0xffffu) | (up << 16);                                     \
    }                                                                               \
    {                                                                               \
        const int buf = (PAR) ^ 1;                                                  \
        if (l < 32 && (l & 4) == 0) {                                               \
            uint64_t* hgrow = hg64 + (((size_t)g * 2 + buf) * 8 + m_ew) * 128;      \
            const uint64_t tagw = ((uint64_t)(uint32_t)(T_ + 1)) << 32;             \
            _Pragma("unroll")                                                       \
            for (int tl = 0; tl < 4; ++tl)                                          \
                AST64(&hgrow[jj[tl] >> 1], tagw | (uint64_t)hpair[tl]);             \
        }                                                                           \
        /* ---- phase B: stage x(T_+1); prefetch x(T_+3) ---- */                    \
        if (m_s < 8) {                                                              \
            _Pragma("unroll")                                                       \
            for (int i = 0; i < 4; ++i) {                                           \
                float4 xv = xb[PAR][i];                                             \
                __half2 h0 = __floats2half2_rn(xv.x, xv.y);                         \
                __half2 h1 = __floats2half2_rn(xv.z, xv.w);                         \
                uint64_t v = (uint64_t)__builtin_bit_cast(uint32_t, h0)             \
                           | ((uint64_t)__builtin_bit_cast(uint32_t, h1) << 32);    \
                int k0 = 256 + d0 + 4 * i;                                          \
                int kk = k0 >> 5, off = k0 & 31;                                    \
                int q = (off & 15) >> 2, hi = off >> 4;                             \
                int slot = (m_s + 16 * q) ^ ((2 * kk) & 63);                        \
                *(uint64_t*)((uint8_t*)hx + kk * 1024 + slot * 16 + hi * 8) = v;    \
            }                                                                       \
            int tn = (T_ + 3 < LSTM_T) ? T_ + 3 : T_;                               \
            const float4* nx = (const float4*)(xrow + (size_t)tn * LSTM_D);         \
            _Pragma("unroll")                                                       \
            for (int i = 0; i < 4; ++i) xb[PAR][i] = nx[i];                         \
        }                                                                           \
        BARLG();   /* barrier1: x(T_+1) staged; all phase-A LDS reads done */       \
        /* issue x-frag reads (independent of poll) */                              \
        uint4 afx[8];                                                               \
        _Pragma("unroll")                                                           \
        for (int kx = 0; kx < 8; ++kx) {                                            \
            int kk = kx + 8;                                                        \
            afx[kx] = hx[kk * 64 + (l ^ ((2 * kk) & 63))];                          \
        }                                                                           \
        /* ---- phase C: poll h(T_+1) -- BATCHED one-cacheline agent read ---- */   \
        if (m_s < 8) {                                                              \
            const uint32_t tgt = (uint32_t)(T_ + 1);                                \
            uint64_t* hgr = hg64 + (((size_t)g * 2 + buf) * 8 + m_s) * 128          \
                          + (d0 >> 1);                                              \
            uint64_t hv[8];                                                         \
            ld64B_agent(hgr, hv);                                                   \
            int spin = 0;                                                           \
            while (true) {                                                          \
                bool ok = true;                                                     \
                _Pragma("unroll")                                                   \
                for (int i = 0; i < 8; ++i) ok &= ((uint32_t)(hv[i] >> 32) >= tgt); \
                if (ok || ++spin > 2000) break;                                     \
                ld64B_agent(hgr, hv);                                               \
            }                                                                       \
            _Pragma("unroll")                                                       \
            for (int i = 0; i < 8; ++i) {                                           \
                uint32_t pr = (uint32_t)hv[i];                                      \
                int k0 = d0 + 2 * i;                                                \
                int kk = k0 >> 5, off = k0 & 31;                                    \
                int q = (off & 15) >> 2, hi = off >> 4;                             \
                int slot = (m_s + 16 * q) ^ ((2 * kk) & 63);                        \
                *(uint32_t*)((uint8_t*)hx + kk * 1024 + slot * 16 + hi * 8          \
                             + ((off & 3) << 1)) = pr;                              \
            }                                                                       \
        }                                                                           \
        /* seed next acc = bias + x(T_+1)-half while the stage drains */            \
        _Pragma("unroll")                                                           \
        for (int tl = 0; tl < 4; ++tl)                                              \
            ACC_N[tl] = (f32x4){bias[tl], bias[tl], bias[tl], bias[tl]};            \
        _Pragma("unroll")                                                           \
        for (int kx = 0; kx < 8; ++kx) {                                            \
            half8 a = __builtin_bit_cast(half8, afx[kx]);                           \
            _Pragma("unroll")                                                       \
            for (int tl = 0; tl < 4; ++tl)                                          \
                ACC_N[tl] = __builtin_amdgcn_mfma_f32_16x16x32_f16(                 \
                    a, __builtin_bit_cast(half8, wf[tl][kx + 8]), ACC_N[tl],        \
                    0, 0, 0);                                                       \
        }                                                                           \
        BARLG();   /* barrier2: h(T_+1) frags visible for next phase A */           \
    }                                                                               \
} while (0)

    for (int t = 0; t < LSTM_T; t += 2) {
        STEP(t,     0, accA, accB);
        STEP(t + 1, 1, accB, accA);
    }
#undef STEP

    if (m_ew < 8) {
        #pragma unroll
        for (int tl = 0; tl < 4; ++tl) {
            int gb = 8 * g + m_ew;
            out[gb * LSTM_H + jj[tl]]                   = hst[tl];
            out[LSTM_B * LSTM_H + gb * LSTM_H + jj[tl]] = cst[tl];
        }
    }
}

extern "C" void kernel_launch(void* const* d_in, const int* in_sizes, int n_in,
                              void* d_out, int out_size, void* d_ws, size_t ws_size,
                              hipStream_t stream) {
    const float* xs   = (const float*)d_in[0];  // [64,4096,256]
    const float* W_ih = (const float*)d_in[1];  // [1024,256]
    const float* W_hh = (const float*)d_in[2];  // [1024,256]
    const float* b    = (const float*)d_in[3];  // [1024]
    float* out = (float*)d_out;
    uint8_t* ws = (uint8_t*)d_ws;

    prep_frags<<<256, 256, 0, stream>>>(W_ih, W_hh, ws);
    lstm_r15<<<32, 256, 0, stream>>>(xs, b, ws, out);
}